// Round 8
// baseline (1149.447 us; speedup 1.0000x reference)
//
#include <hip/hip_runtime.h>

#define NB 2048
#define NT 1024

typedef _Float16 half2_t __attribute__((ext_vector_type(2)));
union F4H { float4 f; half2_t h[4]; };

// sigmoid / tanh via native exp2 + rcp
__device__ __forceinline__ float sig_fast(float x) {
    return __builtin_amdgcn_rcpf(1.0f + __builtin_amdgcn_exp2f(-1.4426950408889634f * x));
}
__device__ __forceinline__ float tanh_fast(float x) {
    return fmaf(2.0f, __builtin_amdgcn_rcpf(1.0f + __builtin_amdgcn_exp2f(-2.8853900817779268f * x)), -1.0f);
}

__global__ void zero_loss_kernel(float* out) { out[0] = 0.0f; }

#define LD4(P, i) (*(const float4*)&(P)[i])
#define FDOT(acc, w, hh) acc = __builtin_amdgcn_fdot2((w), (hh), (acc), false)
#define PINH(v) asm volatile("" : "+v"(v))

// one f32 float4 -> two packed half2
#define CVTQ(n0, n1, p, i) { float4 r_ = LD4(p, i); \
  n0.x=(_Float16)r_.x; n0.y=(_Float16)r_.y; n1.x=(_Float16)r_.z; n1.y=(_Float16)r_.w; }

// one 32-wide weight row as 16 named half2 (16 VGPRs)
#define DECL_ROWH(n, src, row) \
  half2_t n##0,n##1,n##2,n##3,n##4,n##5,n##6,n##7,n##8,n##9,n##10,n##11,n##12,n##13,n##14,n##15; \
  CVTQ(n##0, n##1, src,(row)*32+ 0) CVTQ(n##2, n##3, src,(row)*32+ 4) \
  CVTQ(n##4, n##5, src,(row)*32+ 8) CVTQ(n##6, n##7, src,(row)*32+12) \
  CVTQ(n##8, n##9, src,(row)*32+16) CVTQ(n##10,n##11,src,(row)*32+20) \
  CVTQ(n##12,n##13,src,(row)*32+24) CVTQ(n##14,n##15,src,(row)*32+28) \
  PINH(n##0); PINH(n##1); PINH(n##2); PINH(n##3); PINH(n##4); PINH(n##5); PINH(n##6); PINH(n##7); \
  PINH(n##8); PINH(n##9); PINH(n##10); PINH(n##11); PINH(n##12); PINH(n##13); PINH(n##14); PINH(n##15);

// full 32-wide dot into two interleaved accumulators (8-deep chains)
#define DOT16(a0, a1, n, U0, U1, U2, U3) \
  FDOT(a0, n##0,  (U0).h[0]); FDOT(a1, n##1,  (U0).h[1]); \
  FDOT(a0, n##2,  (U0).h[2]); FDOT(a1, n##3,  (U0).h[3]); \
  FDOT(a0, n##4,  (U1).h[0]); FDOT(a1, n##5,  (U1).h[1]); \
  FDOT(a0, n##6,  (U1).h[2]); FDOT(a1, n##7,  (U1).h[3]); \
  FDOT(a0, n##8,  (U2).h[0]); FDOT(a1, n##9,  (U2).h[1]); \
  FDOT(a0, n##10, (U2).h[2]); FDOT(a1, n##11, (U2).h[3]); \
  FDOT(a0, n##12, (U3).h[0]); FDOT(a1, n##13, (U3).h[1]); \
  FDOT(a0, n##14, (U3).h[2]); FDOT(a1, n##15, (U3).h[3]);

// Block = 2 waves = one sequence. Lane (w,l): gate q=l>>4 of unit u=16w+(l&15),
// i.e. ONE row of each weight matrix -> 48 half2 weight VGPRs. Total demand
// ~100 VGPR < 128: nothing for the allocator to spill/remat, and 4 waves/SIMD
// occupancy (4096 waves total) hides the LDS/barrier latency.
__global__ __launch_bounds__(128)
void decoder_lstm_kernel(const float* __restrict__ seq,    // (B,T,1)
                         const float* __restrict__ z,      // (B,32)
                         const float* __restrict__ w_ih0,  // (128,1)
                         const float* __restrict__ w_hh0,  // (128,32)
                         const float* __restrict__ b_ih0,  // (128,)
                         const float* __restrict__ b_hh0,  // (128,)
                         const float* __restrict__ w_ih1,  // (128,32)
                         const float* __restrict__ w_hh1,  // (128,32)
                         const float* __restrict__ b_ih1,  // (128,)
                         const float* __restrict__ b_hh1,  // (128,)
                         const float* __restrict__ w_out,  // (1,32)
                         const float* __restrict__ b_out,  // (1,)
                         float* __restrict__ out)          // [0]=loss, [1..]=recovered (B,T,1)
{
    const int tid = threadIdx.x;
    const int w   = tid >> 6;          // wave: units [16w, 16w+16)
    const int l   = tid & 63;
    const int q   = l >> 4;            // gate 0=i 1=f 2=g 3=o
    const int u   = 16 * w + (l & 15); // hidden unit
    const int R   = q * 32 + u;        // global gate row
    const int b   = blockIdx.x;

    __shared__ __align__(16) _Float16 h0buf[2][32];   // ping-pong h0
    __shared__ __align__(16) _Float16 h1buf[2][32];   // ping-pong h1
    __shared__ float pb[2];                            // per-wave pred partials

    // 48 half2 = 48 VGPRs of weights (one row of each matrix)
    DECL_ROWH(w0, w_hh0, R)
    DECL_ROWH(wi, w_ih1, R)
    DECL_ROWH(wh, w_hh1, R)

    const float wih0R = w_ih0[R];
    const float bias0 = b_ih0[R] + b_hh0[R];
    const float bias1 = b_ih1[R] + b_hh1[R];

    // activation personality: gate 2 (g) is tanh, others sigmoid
    const float m2 = (q == 2) ? 1.0f : 0.0f;
    const float eM = (q == 2) ? -2.8853900817779268f : -1.4426950408889634f;

    const float wOutL = (l < 16) ? w_out[u] : 0.0f;   // 0 elsewhere -> clean reduce
    const float bOut  = b_out[0];

    // init: h0=c0=h1=c1=z, pred=0. c replicated across the 4 gate lanes of u;
    // only q0 lanes carry the real recurrence (others carry bounded garbage).
    const float cz = z[(size_t)b * 32 + u];
    float c0 = cz, c1 = cz;
    if (l < 16) { h0buf[0][u] = (_Float16)cz; h1buf[0][u] = (_Float16)cz; }
    float pred = 0.0f, sse = 0.0f, xreg = 0.0f;

    const float* seq_b = seq + (size_t)b * NT;
    float* out_b = out + 1 + (size_t)b * NT;

    __syncthreads();

    for (int t = 0; t < NT; ++t) {
        const int par = t & 1;
        if (w == 0 && (t & 63) == 0) xreg = seq_b[t + l];   // coalesced per 64 steps

        // broadcast frag reads (uniform address across wave -> conflict-free)
        F4H U0, U1, U2, U3, X0, X1, X2, X3;
        {
            const float4* p0 = (const float4*)h0buf[par];
            const float4* p1 = (const float4*)h1buf[par];
            U0.f = p0[0]; U1.f = p0[1]; U2.f = p0[2]; U3.f = p0[3];
            X0.f = p1[0]; X1.f = p1[1]; X2.f = p1[2]; X3.f = p1[3];
        }

        // ---- cell 0: v = w_hh0[R].h0 + b0[R] + pred*w_ih0[R]
        float a0 = fmaf(pred, wih0R, bias0), a1 = 0.0f;
        DOT16(a0, a1, w0, U0, U1, U2, U3);
        float v  = a0 + a1;
        float s  = __builtin_amdgcn_rcpf(1.0f + __builtin_amdgcn_exp2f(eM * v));
        float av = fmaf(m2, s - 1.0f, s);           // sig(v) or tanh(v)

        // gate combine, q0-lane mapping (valid on lanes l<16; bounded garbage elsewhere)
        float x16 = __shfl_xor(av, 16);   // sig(f)
        float x32 = __shfl_xor(av, 32);   // tanh(g)
        float x48 = __shfl_xor(av, 48);   // sig(o)
        c0 = fmaf(x16, c0, av * x32);
        float h0n = x48 * tanh_fast(c0);
        if (l < 16) h0buf[par ^ 1][u] = (_Float16)h0n;
        __syncthreads();                 // h0n exchange

        // ---- cell 1: v1 = w_ih1[R].h0n + w_hh1[R].h1 + b1[R]
        F4H V0, V1, V2, V3;
        {
            const float4* p = (const float4*)h0buf[par ^ 1];
            V0.f = p[0]; V1.f = p[1]; V2.f = p[2]; V3.f = p[3];
        }
        float d0 = bias1, d1 = 0.0f, d2 = 0.0f, d3 = 0.0f;
        DOT16(d0, d1, wi, V0, V1, V2, V3);
        DOT16(d2, d3, wh, X0, X1, X2, X3);
        float v1  = (d0 + d1) + (d2 + d3);
        float s1  = __builtin_amdgcn_rcpf(1.0f + __builtin_amdgcn_exp2f(eM * v1));
        float av1 = fmaf(m2, s1 - 1.0f, s1);

        float y16 = __shfl_xor(av1, 16);
        float y32 = __shfl_xor(av1, 32);
        float y48 = __shfl_xor(av1, 48);
        c1 = fmaf(y16, c1, av1 * y32);
        float h1n = y48 * tanh_fast(c1);
        if (l < 16) h1buf[par ^ 1][u] = (_Float16)h1n;

        // pred partial: nonzero only on lanes 0..15 (this wave's 16 units)
        float term = wOutL * h1n;
        term += __shfl_xor(term, 1);
        term += __shfl_xor(term, 2);
        term += __shfl_xor(term, 4);
        term += __shfl_xor(term, 8);
        if (l == 0) pb[w] = term;
        __syncthreads();                 // h1n + pred exchange

        pred = bOut + pb[0] + pb[1];

        if (w == 0) {
            out_b[t] = pred;                          // uniform: 1 transaction
            float d    = xreg - pred;
            float dsel = ((t & 63) == l) ? d : 0.0f;  // lane t&63 owns step t
            sse = fmaf(dsel, d, sse);
        }
    }

    // wave0 SSE reduction, one atomic per block; 1/(B*T) = 2^-21 exact
    if (w == 0) {
        sse += __shfl_xor(sse, 1);
        sse += __shfl_xor(sse, 2);
        sse += __shfl_xor(sse, 4);
        sse += __shfl_xor(sse, 8);
        sse += __shfl_xor(sse, 16);
        sse += __shfl_xor(sse, 32);
        if (l == 0) atomicAdd(out, sse * (1.0f / ((float)NB * (float)NT)));
    }
}

extern "C" void kernel_launch(void* const* d_in, const int* in_sizes, int n_in,
                              void* d_out, int out_size, void* d_ws, size_t ws_size,
                              hipStream_t stream) {
    const float* seq   = (const float*)d_in[0];
    const float* z     = (const float*)d_in[1];
    // d_in[2] = lengths (unused; reference ignores it)
    const float* w_ih0 = (const float*)d_in[3];
    const float* w_hh0 = (const float*)d_in[4];
    const float* b_ih0 = (const float*)d_in[5];
    const float* b_hh0 = (const float*)d_in[6];
    const float* w_ih1 = (const float*)d_in[7];
    const float* w_hh1 = (const float*)d_in[8];
    const float* b_ih1 = (const float*)d_in[9];
    const float* b_hh1 = (const float*)d_in[10];
    const float* w_out = (const float*)d_in[11];
    const float* b_out = (const float*)d_in[12];
    float* out = (float*)d_out;

    hipLaunchKernelGGL(zero_loss_kernel, dim3(1), dim3(1), 0, stream, out);
    hipLaunchKernelGGL(decoder_lstm_kernel, dim3(NB), dim3(128), 0, stream,
                       seq, z, w_ih0, w_hh0, b_ih0, b_hh0,
                       w_ih1, w_hh1, b_ih1, b_hh1, w_out, b_out, out);
}

// Round 9
// 1140.148 us; speedup vs baseline: 1.0082x; 1.0082x over previous
//
#include <hip/hip_runtime.h>

#define NB 2048
#define NT 1024

typedef _Float16 half2_t __attribute__((ext_vector_type(2)));
union F4H { float4 f; half2_t h[4]; };

// sigmoid / tanh via native exp2 + rcp
__device__ __forceinline__ float sig_fast(float x) {
    return __builtin_amdgcn_rcpf(1.0f + __builtin_amdgcn_exp2f(-1.4426950408889634f * x));
}
__device__ __forceinline__ float tanh_fast(float x) {
    return fmaf(2.0f, __builtin_amdgcn_rcpf(1.0f + __builtin_amdgcn_exp2f(-2.8853900817779268f * x)), -1.0f);
}

__global__ void zero_loss_kernel(float* out) { out[0] = 0.0f; }

#define LD4(P, i) (*(const float4*)&(P)[i])
#define FDOT(acc, w, hh) acc = __builtin_amdgcn_fdot2((w), (hh), (acc), false)
#define PINH(v) asm volatile("" : "+v"(v))

// one f32 float4 -> two packed half2
#define CVTQ(n0, n1, p, i) { float4 r_ = LD4(p, i); \
  n0.x=(_Float16)r_.x; n0.y=(_Float16)r_.y; n1.x=(_Float16)r_.z; n1.y=(_Float16)r_.w; }

// one 32-wide weight row as 16 named half2 (16 VGPRs)
#define DECL_ROWH(n, src, row) \
  half2_t n##0,n##1,n##2,n##3,n##4,n##5,n##6,n##7,n##8,n##9,n##10,n##11,n##12,n##13,n##14,n##15; \
  CVTQ(n##0, n##1, src,(row)*32+ 0) CVTQ(n##2, n##3, src,(row)*32+ 4) \
  CVTQ(n##4, n##5, src,(row)*32+ 8) CVTQ(n##6, n##7, src,(row)*32+12) \
  CVTQ(n##8, n##9, src,(row)*32+16) CVTQ(n##10,n##11,src,(row)*32+20) \
  CVTQ(n##12,n##13,src,(row)*32+24) CVTQ(n##14,n##15,src,(row)*32+28) \
  PINH(n##0); PINH(n##1); PINH(n##2); PINH(n##3); PINH(n##4); PINH(n##5); PINH(n##6); PINH(n##7); \
  PINH(n##8); PINH(n##9); PINH(n##10); PINH(n##11); PINH(n##12); PINH(n##13); PINH(n##14); PINH(n##15);

// full 32-wide dot into two interleaved accumulators (8-deep chains)
#define DOT16(a0, a1, n, U0, U1, U2, U3) \
  FDOT(a0, n##0,  (U0).h[0]); FDOT(a1, n##1,  (U0).h[1]); \
  FDOT(a0, n##2,  (U0).h[2]); FDOT(a1, n##3,  (U0).h[3]); \
  FDOT(a0, n##4,  (U1).h[0]); FDOT(a1, n##5,  (U1).h[1]); \
  FDOT(a0, n##6,  (U1).h[2]); FDOT(a1, n##7,  (U1).h[3]); \
  FDOT(a0, n##8,  (U2).h[0]); FDOT(a1, n##9,  (U2).h[1]); \
  FDOT(a0, n##10, (U2).h[2]); FDOT(a1, n##11, (U2).h[3]); \
  FDOT(a0, n##12, (U3).h[0]); FDOT(a1, n##13, (U3).h[1]); \
  FDOT(a0, n##14, (U3).h[2]); FDOT(a1, n##15, (U3).h[3]);

// Block = 2 waves = one sequence; lane (w,l) owns gate q=l>>4 of unit
// u=16w+(l&15) -> 48 half2 weight VGPRs. Grid gives exactly 4 waves/SIMD, so
// pin the occupancy target AND cap there: waves_per_eu(4,4) -> 128-VGPR
// budget. Demand (~100) < budget for the FIRST time across rounds: the
// scheduler has no occupancy reason to remat/offload the pinned weights.
__global__ __launch_bounds__(128) __attribute__((amdgpu_waves_per_eu(4, 4)))
void decoder_lstm_kernel(const float* __restrict__ seq,    // (B,T,1)
                         const float* __restrict__ z,      // (B,32)
                         const float* __restrict__ w_ih0,  // (128,1)
                         const float* __restrict__ w_hh0,  // (128,32)
                         const float* __restrict__ b_ih0,  // (128,)
                         const float* __restrict__ b_hh0,  // (128,)
                         const float* __restrict__ w_ih1,  // (128,32)
                         const float* __restrict__ w_hh1,  // (128,32)
                         const float* __restrict__ b_ih1,  // (128,)
                         const float* __restrict__ b_hh1,  // (128,)
                         const float* __restrict__ w_out,  // (1,32)
                         const float* __restrict__ b_out,  // (1,)
                         float* __restrict__ out)          // [0]=loss, [1..]=recovered (B,T,1)
{
    const int tid = threadIdx.x;
    const int w   = tid >> 6;          // wave: units [16w, 16w+16)
    const int l   = tid & 63;
    const int q   = l >> 4;            // gate 0=i 1=f 2=g 3=o
    const int u   = 16 * w + (l & 15); // hidden unit
    const int R   = q * 32 + u;        // global gate row
    const int b   = blockIdx.x;

    __shared__ __align__(16) _Float16 h0buf[2][32];   // ping-pong h0
    __shared__ __align__(16) _Float16 h1buf[2][32];   // ping-pong h1
    __shared__ float pb[2];                            // per-wave pred partials

    // 48 half2 = 48 VGPRs of weights (one row of each matrix)
    DECL_ROWH(w0, w_hh0, R)
    DECL_ROWH(wi, w_ih1, R)
    DECL_ROWH(wh, w_hh1, R)

    const float wih0R = w_ih0[R];
    const float bias0 = b_ih0[R] + b_hh0[R];
    const float bias1 = b_ih1[R] + b_hh1[R];

    // activation personality: gate 2 (g) is tanh, others sigmoid
    const float m2 = (q == 2) ? 1.0f : 0.0f;
    const float eM = (q == 2) ? -2.8853900817779268f : -1.4426950408889634f;

    const float wOutL = (l < 16) ? w_out[u] : 0.0f;   // 0 elsewhere -> clean reduce
    const float bOut  = b_out[0];

    // init: h0=c0=h1=c1=z, pred=0. c replicated across the 4 gate lanes of u;
    // only q0 lanes carry the real recurrence (others carry bounded garbage).
    const float cz = z[(size_t)b * 32 + u];
    float c0 = cz, c1 = cz;
    if (l < 16) { h0buf[0][u] = (_Float16)cz; h1buf[0][u] = (_Float16)cz; }
    float pred = 0.0f, sse = 0.0f, xreg = 0.0f;

    const float* seq_b = seq + (size_t)b * NT;
    float* out_b = out + 1 + (size_t)b * NT;

    __syncthreads();

    for (int t = 0; t < NT; ++t) {
        const int par = t & 1;
        if (w == 0 && (t & 63) == 0) xreg = seq_b[t + l];   // coalesced per 64 steps

        // broadcast frag reads for cell 0 (uniform address -> conflict-free)
        F4H U0, U1, U2, U3;
        {
            const float4* p0 = (const float4*)h0buf[par];
            U0.f = p0[0]; U1.f = p0[1]; U2.f = p0[2]; U3.f = p0[3];
        }

        // ---- cell 0: v = w_hh0[R].h0 + b0[R] + pred*w_ih0[R]
        float a0 = fmaf(pred, wih0R, bias0), a1 = 0.0f;
        DOT16(a0, a1, w0, U0, U1, U2, U3);
        float v  = a0 + a1;
        float s  = __builtin_amdgcn_rcpf(1.0f + __builtin_amdgcn_exp2f(eM * v));
        float av = fmaf(m2, s - 1.0f, s);           // sig(v) or tanh(v)

        // gate combine, q0-lane mapping (valid on lanes l<16; bounded garbage elsewhere)
        float x16 = __shfl_xor(av, 16);   // sig(f)
        float x32 = __shfl_xor(av, 32);   // tanh(g)
        float x48 = __shfl_xor(av, 48);   // sig(o)
        c0 = fmaf(x16, c0, av * x32);
        float h0n = x48 * tanh_fast(c0);
        if (l < 16) h0buf[par ^ 1][u] = (_Float16)h0n;
        __syncthreads();                 // h0n exchange

        // ---- cell 1: v1 = w_ih1[R].h0n + w_hh1[R].h1 + b1[R]
        // h1 frags read AFTER the barrier (ping-pong: reads par, writes par^1)
        // to keep them out of cell 0's live range.
        F4H V0, V1, V2, V3, X0, X1, X2, X3;
        {
            const float4* p  = (const float4*)h0buf[par ^ 1];
            const float4* p1 = (const float4*)h1buf[par];
            V0.f = p[0];  V1.f = p[1];  V2.f = p[2];  V3.f = p[3];
            X0.f = p1[0]; X1.f = p1[1]; X2.f = p1[2]; X3.f = p1[3];
        }
        float d0 = bias1, d1 = 0.0f, d2 = 0.0f, d3 = 0.0f;
        DOT16(d0, d1, wi, V0, V1, V2, V3);
        DOT16(d2, d3, wh, X0, X1, X2, X3);
        float v1  = (d0 + d1) + (d2 + d3);
        float s1  = __builtin_amdgcn_rcpf(1.0f + __builtin_amdgcn_exp2f(eM * v1));
        float av1 = fmaf(m2, s1 - 1.0f, s1);

        float y16 = __shfl_xor(av1, 16);
        float y32 = __shfl_xor(av1, 32);
        float y48 = __shfl_xor(av1, 48);
        c1 = fmaf(y16, c1, av1 * y32);
        float h1n = y48 * tanh_fast(c1);
        if (l < 16) h1buf[par ^ 1][u] = (_Float16)h1n;

        // pred partial: nonzero only on lanes 0..15 (this wave's 16 units)
        float term = wOutL * h1n;
        term += __shfl_xor(term, 1);
        term += __shfl_xor(term, 2);
        term += __shfl_xor(term, 4);
        term += __shfl_xor(term, 8);
        if (l == 0) pb[w] = term;
        __syncthreads();                 // h1n + pred exchange

        pred = bOut + pb[0] + pb[1];

        if (w == 0) {
            out_b[t] = pred;                          // uniform: 1 transaction
            float d    = xreg - pred;
            float dsel = ((t & 63) == l) ? d : 0.0f;  // lane t&63 owns step t
            sse = fmaf(dsel, d, sse);
        }
    }

    // wave0 SSE reduction, one atomic per block; 1/(B*T) = 2^-21 exact
    if (w == 0) {
        sse += __shfl_xor(sse, 1);
        sse += __shfl_xor(sse, 2);
        sse += __shfl_xor(sse, 4);
        sse += __shfl_xor(sse, 8);
        sse += __shfl_xor(sse, 16);
        sse += __shfl_xor(sse, 32);
        if (l == 0) atomicAdd(out, sse * (1.0f / ((float)NB * (float)NT)));
    }
}

extern "C" void kernel_launch(void* const* d_in, const int* in_sizes, int n_in,
                              void* d_out, int out_size, void* d_ws, size_t ws_size,
                              hipStream_t stream) {
    const float* seq   = (const float*)d_in[0];
    const float* z     = (const float*)d_in[1];
    // d_in[2] = lengths (unused; reference ignores it)
    const float* w_ih0 = (const float*)d_in[3];
    const float* w_hh0 = (const float*)d_in[4];
    const float* b_ih0 = (const float*)d_in[5];
    const float* b_hh0 = (const float*)d_in[6];
    const float* w_ih1 = (const float*)d_in[7];
    const float* w_hh1 = (const float*)d_in[8];
    const float* b_ih1 = (const float*)d_in[9];
    const float* b_hh1 = (const float*)d_in[10];
    const float* w_out = (const float*)d_in[11];
    const float* b_out = (const float*)d_in[12];
    float* out = (float*)d_out;

    hipLaunchKernelGGL(zero_loss_kernel, dim3(1), dim3(1), 0, stream, out);
    hipLaunchKernelGGL(decoder_lstm_kernel, dim3(NB), dim3(128), 0, stream,
                       seq, z, w_ih0, w_hh0, b_ih0, b_hh0,
                       w_ih1, w_hh1, b_ih1, b_hh1, w_out, b_out, out);
}